// Round 16
// baseline (686.697 us; speedup 1.0000x reference)
//
#include <hip/hip_runtime.h>
#include <math.h>

#define T_LEN   2048
#define B_ROWS  4096
#define F_IN    16
#define HID     32
#define NCH     12
#define L_OUT   1023
#define TCH     8                  // timesteps per chunk
#define NCHUNK  (T_LEN / TCH)      // 256
#define RRELU_SLOPE 0.229f
#define ZSCALE  2.8853900817779268f   // 2*log2(e), folded into W_ih/W_hh/biases

typedef _Float16 half4 __attribute__((ext_vector_type(4)));
typedef _Float16 half8 __attribute__((ext_vector_type(8)));
typedef float    f32x4 __attribute__((ext_vector_type(4)));

// mfma_f32_16x16x16f16 (R7-R15 validated on gfx950):
// A: row = lane&15, k = 4*(lane>>4)+i ; B: col = lane&15, k = 4*(lane>>4)+i
// D: col = lane&15, row = 4*(lane>>4)+reg  -> D layout == next B layout
__device__ __forceinline__ f32x4 mfma16(half4 a, half4 b, f32x4 c) {
    return __builtin_amdgcn_mfma_f32_16x16x16f16(a, b, c, 0, 0, 0);
}

// K=32 fragment = concat of two K=16 fragments (R12-validated on gfx950).
__device__ __forceinline__ f32x4 hmfma32(half8 a, half8 b, f32x4 c) {
#if __has_builtin(__builtin_amdgcn_mfma_f32_16x16x32_f16)
    return __builtin_amdgcn_mfma_f32_16x16x32_f16(a, b, c, 0, 0, 0);
#else
    const uint4 ua = __builtin_bit_cast(uint4, a);
    const uint4 ub = __builtin_bit_cast(uint4, b);
    uint2 t;
    t.x = ua.x; t.y = ua.y; const half4 alo = __builtin_bit_cast(half4, t);
    t.x = ua.z; t.y = ua.w; const half4 ahi = __builtin_bit_cast(half4, t);
    t.x = ub.x; t.y = ub.y; const half4 blo = __builtin_bit_cast(half4, t);
    t.x = ub.z; t.y = ub.w; const half4 bhi = __builtin_bit_cast(half4, t);
    return mfma16(ahi, bhi, mfma16(alo, blo, c));
#endif
}

__device__ __forceinline__ unsigned pk2u(float a, float b) {
    return __builtin_bit_cast(unsigned, __builtin_amdgcn_cvt_pkrtz(a, b));
}
__device__ __forceinline__ half4 pack4(float a, float b, float c, float d) {
    uint2 u; u.x = pk2u(a, b); u.y = pk2u(c, d);
    return __builtin_bit_cast(half4, u);
}
__device__ __forceinline__ uint4 u4(f32x4 v) { return __builtin_bit_cast(uint4, v); }
__device__ __forceinline__ f32x4 f4(uint4 v) { return __builtin_bit_cast(f32x4, v); }

// Raw barrier + LDS drain only. __syncthreads would drain vmcnt(0) too and
// expose wave1's in-flight global x-loads at EVERY slot barrier.
#define STEP_SYNC() asm volatile("s_waitcnt lgkmcnt(0)\n\ts_barrier" ::: "memory")

// Four waves per chain:
//   wave0a: recurrence units 0-15  (1 K=32 MFMA + 4 tanh, h-half exchange)
//   wave0b: recurrence units 16-31 (symmetric)
//   wave1 : x-prep, 1 timestep/slot (global load + 2 K=16 x-MFMAs -> LDS)
//   wave2 : proj/pool, 1 timestep/slot, one chunk behind
// Barrier every step orders the h-half exchange; trans issue per wave is
// 6x16=96 cyc/step (was 16x16=256 on one wave).
__global__ __launch_bounds__(256, 1)
void rnn_mfma_kernel(const float* __restrict__ x,
                     const float* __restrict__ W_ih,
                     const float* __restrict__ W_hh,
                     const float* __restrict__ b_ih,
                     const float* __restrict__ b_hh,
                     const float* __restrict__ W_proj,
                     const float* __restrict__ b_proj,
                     float* __restrict__ out)
{
    __shared__ alignas(16) uint4 hqs[2][TCH][64];    // packed h (xy=lo, zw=hi)
    __shared__ alignas(16) uint4 xza_s[2][TCH][64];  // xz' units 0-15 (f32x4)
    __shared__ alignas(16) uint4 xzb_s[2][TCH][64];  // xz' units 16-31
    __shared__ alignas(16) float pbuf[64];           // wave2 cross-g partials

    const int tid  = threadIdx.x;
    const int wid  = tid >> 6;         // 0,1 = recurrence halves; 2 = x-prep; 3 = proj
    const int lane = tid & 63;
    const int c16  = lane & 15;
    const int g    = lane >> 4;
    const int rowBase = blockIdx.x * 16;

    const f32x4 zero4 = {0.0f, 0.0f, 0.0f, 0.0f};
    const float4* xsrc = (const float4*)x;
    const size_t xrow = (size_t)(rowBase + c16) * T_LEN;
    float* outrow = out + (size_t)(rowBase + c16) * L_OUT;

    // ---- per-role weights ----
    const int U = wid;                 // recurrence half index (valid for wid<=1)
    half8 AhhF = {0,0,0,0,0,0,0,0};
    half4 Aih[2];
    half8 ApF;
    f32x4 biasA = zero4, biasB = zero4, biasP = zero4;
    float4 xsA[TCH], xsB[TCH];

    if (wid <= 1) {
        #pragma unroll
        for (int V = 0; V < 2; ++V)
            #pragma unroll
            for (int i = 0; i < 4; ++i)
                AhhF[V*4 + i] = (_Float16)(ZSCALE *
                    W_hh[(U*16 + c16)*HID + V*16 + 4*g + i]);
    } else if (wid == 2) {
        #pragma unroll
        for (int Uu = 0; Uu < 2; ++Uu)
            #pragma unroll
            for (int i = 0; i < 4; ++i)
                Aih[Uu][i] = (_Float16)(ZSCALE *
                    W_ih[(Uu*16 + c16)*F_IN + 4*g + i]);
        #pragma unroll
        for (int r = 0; r < 4; ++r) {
            const int u = 4*g + r;
            biasA[r] = ZSCALE * (b_ih[u]      + b_hh[u]);
            biasB[r] = ZSCALE * (b_ih[16 + u] + b_hh[16 + u]);
        }
    } else {
        #pragma unroll
        for (int V = 0; V < 2; ++V)
            #pragma unroll
            for (int i = 0; i < 4; ++i)
                ApF[V*4 + i] = (c16 < NCH)
                    ? (_Float16)W_proj[c16*HID + V*16 + 4*g + i]
                    : (_Float16)0.0f;
        #pragma unroll
        for (int r = 0; r < 4; ++r) {
            const int u = 4*g + r;
            biasP[r] = (u < NCH) ? b_proj[u] : 0.0f;
        }
    }

    half8 Bh = {0,0,0,0,0,0,0,0};      // recurrence state (full 32 units packed)
    uint4 xz_cur;                      // prefetched xz' for this wave's half
    f32x4 Wc = zero4;                  // wave2 pool window accumulator
    const uint4* xz_base = (U == 0) ? &xza_s[0][0][0] : &xzb_s[0][0][0];

    // ---- recurrence wave: compute phase of one slot ----
    auto w0_compute = [&](int buf, int tt) {
        const f32x4 z = hmfma32(AhhF, Bh, f4(xz_cur));
        // prefetch next slot's xz' (issued early, independent)
        const int nbuf = (tt < TCH-1) ? buf : (buf ^ 1);
        const int ntt  = (tt < TCH-1) ? tt + 1 : 0;
        xz_cur = xz_base[(nbuf*TCH + ntt)*64 + lane];
        // tanh x4, paired rcp: 4 exp2 + 2 rcp (trans) + 14 VALU
        const float e0 = __builtin_amdgcn_exp2f(z[0]);
        const float e1 = __builtin_amdgcn_exp2f(z[1]);
        const float e2 = __builtin_amdgcn_exp2f(z[2]);
        const float e3 = __builtin_amdgcn_exp2f(z[3]);
        const float d0 = e0 + 1.0f, d1 = e1 + 1.0f;
        const float d2 = e2 + 1.0f, d3 = e3 + 1.0f;
        const float r01 = __builtin_amdgcn_rcpf(d0 * d1);
        const float r23 = __builtin_amdgcn_rcpf(d2 * d3);
        const float i0 = d1 * r01, i1 = d0 * r01;
        const float i2 = d3 * r23, i3 = d2 * r23;
        const float h0 = fmaf(-2.0f, i0, 1.0f);
        const float h1 = fmaf(-2.0f, i1, 1.0f);
        const float h2 = fmaf(-2.0f, i2, 1.0f);
        const float h3 = fmaf(-2.0f, i3, 1.0f);
        uint2 own; own.x = pk2u(h0, h1); own.y = pk2u(h2, h3);
        ((uint2*)&hqs[buf][tt][lane])[U] = own;   // publish this half (b64)
    };
    // after the slot barrier: read the full packed h (both halves) as next B
    auto w0_after = [&](int buf, int tt) {
        Bh = __builtin_bit_cast(half8, hqs[buf][tt][lane]);
    };

    // ---- wave1: one timestep of x-prep per slot ----
    auto w1_slot = [&](int buf, int tt, const float4* xs_use, float4* xs_fill,
                       int loadchunk) {
        const int cc2 = (loadchunk < NCHUNK) ? loadchunk : NCHUNK - 1;
        xs_fill[tt] = xsrc[(xrow + (size_t)cc2*TCH + tt) * 4 + g];
        const half4 Bx = pack4(xs_use[tt].x, xs_use[tt].y,
                               xs_use[tt].z, xs_use[tt].w);
        xza_s[buf][tt][lane] = u4(mfma16(Aih[0], Bx, biasA));
        xzb_s[buf][tt][lane] = u4(mfma16(Aih[1], Bx, biasB));
    };

    // ---- wave2: one timestep of proj+pool per slot ----
    const half8 sl8 = {(_Float16)RRELU_SLOPE, (_Float16)RRELU_SLOPE,
                       (_Float16)RRELU_SLOPE, (_Float16)RRELU_SLOPE,
                       (_Float16)RRELU_SLOPE, (_Float16)RRELU_SLOPE,
                       (_Float16)RRELU_SLOPE, (_Float16)RRELU_SLOPE};
    auto w2_slot = [&](int c, int buf, int tt) {
        const int t = c*TCH + tt;
        const uint4 hv = hqs[buf][tt][lane];
        const half8 h8 = __builtin_bit_cast(half8, hv);
        const half8 a8 = __builtin_elementwise_max(h8, h8 * sl8); // eval RReLU
        const f32x4 p  = hmfma32(ApF, a8, biasP);
        const f32x4 q4 = p * p;
        if ((tt & 1) == 0) {                 // t even (chunk base even)
            const f32x4 pr = Wc + q4;        // closes window t/2 - 1
            if (t >= 2) {
                const float mloc = fmaxf(fmaxf(pr[0], pr[1]),
                                         fmaxf(pr[2], pr[3]));
                pbuf[c16*4 + g] = mloc;      // intra-wave, DS FIFO ordered
                if (g == 0) {
                    const f32x4 pv = *(const f32x4*)&pbuf[c16*4];
                    const float mm = fmaxf(fmaxf(pv[0], pv[1]),
                                           fmaxf(pv[2], pv[3]));
                    outrow[(t >> 1) - 1] = __builtin_amdgcn_sqrtf(mm);
                }
            }
            Wc = q4;                         // opens window t/2
        } else {
            Wc = Wc + q4;
        }
    };

    // ---- prologue: wave1 fills chunk 0 -> buf0, prefetches chunk 1 -> xsA ----
    if (wid == 2) {
        float4 x0[TCH];
        #pragma unroll
        for (int m = 0; m < TCH; ++m)
            x0[m] = xsrc[(xrow + m) * 4 + g];
        #pragma unroll
        for (int m = 0; m < TCH; ++m) {
            const half4 Bx = pack4(x0[m].x, x0[m].y, x0[m].z, x0[m].w);
            xza_s[0][m][lane] = u4(mfma16(Aih[0], Bx, biasA));
            xzb_s[0][m][lane] = u4(mfma16(Aih[1], Bx, biasB));
        }
        #pragma unroll
        for (int m = 0; m < TCH; ++m)
            xsA[m] = xsrc[(xrow + TCH + m) * 4 + g];
    }
    STEP_SYNC();
    if (wid <= 1)
        xz_cur = xz_base[lane];        // [buf0][tt0]

    // ---- main loop (NCHUNK even), buffers static via x2 unroll ----
    for (int cc = 0; cc < NCHUNK; cc += 2) {
        // sub A: chunk cc (xz/h in buf0); w1 -> chunk cc+1 (buf1), loads cc+2;
        //        w2 -> chunk cc-1 (buf1)
        #pragma unroll
        for (int tt = 0; tt < TCH; ++tt) {
            if (wid <= 1)        w0_compute(0, tt);
            else if (wid == 2)   w1_slot(1, tt, xsA, xsB, cc + 2);
            else if (cc > 0)     w2_slot(cc - 1, 1, tt);
            STEP_SYNC();
            if (wid <= 1)        w0_after(0, tt);
        }
        // sub B: chunk cc+1 (buf1); w1 -> chunk cc+2 (buf0), loads cc+3;
        //        w2 -> chunk cc (buf0)
        #pragma unroll
        for (int tt = 0; tt < TCH; ++tt) {
            if (wid <= 1)        w0_compute(1, tt);
            else if (wid == 2)   w1_slot(0, tt, xsB, xsA, cc + 3);
            else                 w2_slot(cc, 0, tt);
            STEP_SYNC();
            if (wid <= 1)        w0_after(1, tt);
        }
    }
    // epilogue: wave2 finishes the last chunk (NCHUNK-1, odd -> buf1)
    if (wid == 3) {
        #pragma unroll
        for (int tt = 0; tt < TCH; ++tt)
            w2_slot(NCHUNK - 1, 1, tt);
    }
}

extern "C" void kernel_launch(void* const* d_in, const int* in_sizes, int n_in,
                              void* d_out, int out_size, void* d_ws, size_t ws_size,
                              hipStream_t stream) {
    const float* x      = (const float*)d_in[0];
    const float* W_ih   = (const float*)d_in[1];
    const float* W_hh   = (const float*)d_in[2];
    const float* b_ih   = (const float*)d_in[3];
    const float* b_hh   = (const float*)d_in[4];
    const float* W_proj = (const float*)d_in[5];
    const float* b_proj = (const float*)d_in[6];
    float* out = (float*)d_out;

    dim3 grid(B_ROWS / 16);   // 256 chains; 4 waves (4 SIMDs) per chain
    dim3 block(256);
    hipLaunchKernelGGL(rnn_mfma_kernel, grid, block, 0, stream,
                       x, W_ih, W_hh, b_ih, b_hh, W_proj, b_proj, out);
}

// Round 17
// 330.520 us; speedup vs baseline: 2.0776x; 2.0776x over previous
//
#include <hip/hip_runtime.h>
#include <math.h>

#define T_LEN   2048
#define B_ROWS  4096
#define F_IN    16
#define HID     32
#define NCH     12
#define L_OUT   1023
#define TCH     16                 // timesteps per chunk (= sync granularity)
#define NCHUNK  (T_LEN / TCH)
#define RRELU_SLOPE 0.229f
#define ZSCALE  2.8853900817779268f   // 2*log2(e), folded into W_ih/W_hh/biases

typedef _Float16 half4 __attribute__((ext_vector_type(4)));
typedef _Float16 half8 __attribute__((ext_vector_type(8)));
typedef float    f32x4 __attribute__((ext_vector_type(4)));

// mfma_f32_16x16x16f16 (R7-R15 validated on gfx950):
// A: row = lane&15, k = 4*(lane>>4)+i ; B: col = lane&15, k = 4*(lane>>4)+i
// D: col = lane&15, row = 4*(lane>>4)+reg  -> D layout == next B layout
__device__ __forceinline__ f32x4 mfma16(half4 a, half4 b, f32x4 c) {
    return __builtin_amdgcn_mfma_f32_16x16x16f16(a, b, c, 0, 0, 0);
}

// K=32 fragment = concat of two K=16 fragments (R12-validated on gfx950).
__device__ __forceinline__ f32x4 hmfma32(half8 a, half8 b, f32x4 c) {
#if __has_builtin(__builtin_amdgcn_mfma_f32_16x16x32_f16)
    return __builtin_amdgcn_mfma_f32_16x16x32_f16(a, b, c, 0, 0, 0);
#else
    const uint4 ua = __builtin_bit_cast(uint4, a);
    const uint4 ub = __builtin_bit_cast(uint4, b);
    uint2 t;
    t.x = ua.x; t.y = ua.y; const half4 alo = __builtin_bit_cast(half4, t);
    t.x = ua.z; t.y = ua.w; const half4 ahi = __builtin_bit_cast(half4, t);
    t.x = ub.x; t.y = ub.y; const half4 blo = __builtin_bit_cast(half4, t);
    t.x = ub.z; t.y = ub.w; const half4 bhi = __builtin_bit_cast(half4, t);
    return mfma16(ahi, bhi, mfma16(alo, blo, c));
#endif
}

__device__ __forceinline__ unsigned pk2u(float a, float b) {
    return __builtin_bit_cast(unsigned, __builtin_amdgcn_cvt_pkrtz(a, b));
}
__device__ __forceinline__ half4 pack4(float a, float b, float c, float d) {
    uint2 u; u.x = pk2u(a, b); u.y = pk2u(c, d);
    return __builtin_bit_cast(half4, u);
}
__device__ __forceinline__ uint4 u4(f32x4 v) { return __builtin_bit_cast(uint4, v); }
__device__ __forceinline__ f32x4 f4(uint4 v) { return __builtin_bit_cast(f32x4, v); }

// Three waves per chain (three SIMDs) -- exact R12 structure (309 us best).
// Only wave0's tanh block differs: Montgomery batched reciprocal turns the
// 8 per-step v_rcp_f32 into 1 rcp + 20 muls (trans 16 -> 9 per step).
__global__ __launch_bounds__(192, 1)
void rnn_mfma_kernel(const float* __restrict__ x,
                     const float* __restrict__ W_ih,
                     const float* __restrict__ W_hh,
                     const float* __restrict__ b_ih,
                     const float* __restrict__ b_hh,
                     const float* __restrict__ W_proj,
                     const float* __restrict__ b_proj,
                     float* __restrict__ out)
{
    __shared__ alignas(16) uint4 hqs[2][TCH][64];    // packed h,   32 KB
    __shared__ alignas(16) uint4 xza_s[2][TCH][64];  // xz' lo blk, 32 KB (f32x4)
    __shared__ alignas(16) uint4 xzb_s[2][TCH][64];  // xz' hi blk, 32 KB
    __shared__ alignas(16) float pbuf[64];           // wave2 cross-g partials

    const int tid  = threadIdx.x;
    const int wid  = tid >> 6;         // 0=recurrence, 1=x-prep, 2=proj/pool
    const int lane = tid & 63;
    const int c16  = lane & 15;        // batch column
    const int g    = lane >> 4;        // k-block / D row-block
    const int rowBase = blockIdx.x * 16;

    const f32x4 zero4 = {0.0f, 0.0f, 0.0f, 0.0f};

    const float4* xsrc = (const float4*)x;
    const size_t xrow = (size_t)(rowBase + c16) * T_LEN;
    float* outrow = out + (size_t)(rowBase + c16) * L_OUT;

    // ---- per-wave weight fragments ----
    half8 AhhF[2];                     // K=32 fragments for the two unit-blocks
    half4 Aih[2];
    half8 ApF;
    f32x4 biasA = zero4, biasB = zero4, biasP = zero4;
    float4 xsA[TCH], xsB[TCH];         // wave1 load ping-pong

    if (wid == 0) {
        #pragma unroll
        for (int U = 0; U < 2; ++U) {
            half8 f;
            #pragma unroll
            for (int V = 0; V < 2; ++V)
                #pragma unroll
                for (int i = 0; i < 4; ++i)
                    f[V*4 + i] = (_Float16)(ZSCALE *
                        W_hh[(U*16 + c16)*HID + V*16 + 4*g + i]);
            AhhF[U] = f;
        }
    } else if (wid == 1) {
        #pragma unroll
        for (int U = 0; U < 2; ++U)
            #pragma unroll
            for (int i = 0; i < 4; ++i)
                Aih[U][i] = (_Float16)(ZSCALE *
                    W_ih[(U*16 + c16)*F_IN + 4*g + i]);
        #pragma unroll
        for (int r = 0; r < 4; ++r) {
            const int u = 4*g + r;
            biasA[r] = ZSCALE * (b_ih[u]      + b_hh[u]);
            biasB[r] = ZSCALE * (b_ih[16 + u] + b_hh[16 + u]);
        }
    } else {
        #pragma unroll
        for (int V = 0; V < 2; ++V)
            #pragma unroll
            for (int i = 0; i < 4; ++i)
                ApF[V*4 + i] = (c16 < NCH)
                    ? (_Float16)W_proj[c16*HID + V*16 + 4*g + i]
                    : (_Float16)0.0f;
        #pragma unroll
        for (int r = 0; r < 4; ++r) {
            const int u = 4*g + r;
            biasP[r] = (u < NCH) ? b_proj[u] : 0.0f;  // pad rows -> p=0 (max-safe)
        }
    }

    // wave0 recurrent state: h as the K=32 B fragment (lo16 | hi16)
    half8 Bh = {0,0,0,0,0,0,0,0};
    f32x4 Wc = zero4;                  // wave2 pool window accumulator

    // ---- wave1 helpers ----
    auto w1_load = [&](int c, float4* xs) {
        const int cc = (c < NCHUNK) ? c : NCHUNK - 1;
        #pragma unroll
        for (int m = 0; m < TCH; ++m)
            xs[m] = xsrc[(xrow + cc*TCH + m) * 4 + g];
    };
    auto w1_compute = [&](int buf, const float4* xs) {
        #pragma unroll
        for (int m = 0; m < TCH; ++m) {
            const half4 Bx = pack4(xs[m].x, xs[m].y, xs[m].z, xs[m].w);
            xza_s[buf][m][lane] = u4(mfma16(Aih[0], Bx, biasA));
            xzb_s[buf][m][lane] = u4(mfma16(Aih[1], Bx, biasB));
        }
    };

    // ---- wave0: one chunk of the sequential core (4-deep xz prefetch) ----
    auto w0_chunk = [&](int buf) {
        uint4 ra[4], rb[4];
        #pragma unroll
        for (int i = 0; i < 4; ++i) {
            ra[i] = xza_s[buf][i][lane];
            rb[i] = xzb_s[buf][i][lane];
        }
        #pragma unroll
        for (int tt = 0; tt < TCH; ++tt) {
            const f32x4 xza = f4(ra[tt & 3]);
            const f32x4 xzb = f4(rb[tt & 3]);
            // two independent K=32 MFMAs: z' = ZSCALE*(W*[x;h] + bias)
            const f32x4 za = hmfma32(AhhF[0], Bh, xza);
            const f32x4 zb = hmfma32(AhhF[1], Bh, xzb);
            if (tt + 4 < TCH) {                 // prefetch 4 steps ahead
                ra[tt & 3] = xza_s[buf][tt + 4][lane];
                rb[tt & 3] = xzb_s[buf][tt + 4][lane];
            }
            // tanh = 1 - 2/(exp2(z') + 1), with ONE batched reciprocal:
            // Montgomery inverse over the 8 denominators (1 rcp + 20 muls).
            const float e0 = __builtin_amdgcn_exp2f(za[0]);
            const float e1 = __builtin_amdgcn_exp2f(za[1]);
            const float e2 = __builtin_amdgcn_exp2f(za[2]);
            const float e3 = __builtin_amdgcn_exp2f(za[3]);
            const float e4 = __builtin_amdgcn_exp2f(zb[0]);
            const float e5 = __builtin_amdgcn_exp2f(zb[1]);
            const float e6 = __builtin_amdgcn_exp2f(zb[2]);
            const float e7 = __builtin_amdgcn_exp2f(zb[3]);
            const float d0 = e0 + 1.0f, d1 = e1 + 1.0f;
            const float d2 = e2 + 1.0f, d3 = e3 + 1.0f;
            const float d4 = e4 + 1.0f, d5 = e5 + 1.0f;
            const float d6 = e6 + 1.0f, d7 = e7 + 1.0f;
            const float p1 = d0 * d1;          // prefix products
            const float p2 = p1 * d2;
            const float p3 = p2 * d3;
            const float p4 = p3 * d4;
            const float p5 = p4 * d5;
            const float p6 = p5 * d6;
            const float p7 = p6 * d7;          // <= ~3e14, no overflow
            float q = __builtin_amdgcn_rcpf(p7);
            const float i7 = p6 * q;  q = d7 * q;
            const float i6 = p5 * q;  q = d6 * q;
            const float i5 = p4 * q;  q = d5 * q;
            const float i4 = p3 * q;  q = d4 * q;
            const float i3 = p2 * q;  q = d3 * q;
            const float i2 = p1 * q;  q = d2 * q;
            const float i1 = d0 * q;
            const float i0 = d1 * q;
            const float h0 = fmaf(-2.0f, i0, 1.0f);
            const float h1 = fmaf(-2.0f, i1, 1.0f);
            const float h2 = fmaf(-2.0f, i2, 1.0f);
            const float h3 = fmaf(-2.0f, i3, 1.0f);
            const float h4 = fmaf(-2.0f, i4, 1.0f);
            const float h5 = fmaf(-2.0f, i5, 1.0f);
            const float h6 = fmaf(-2.0f, i6, 1.0f);
            const float h7 = fmaf(-2.0f, i7, 1.0f);
            uint4 hp;
            hp.x = pk2u(h0, h1);
            hp.y = pk2u(h2, h3);
            hp.z = pk2u(h4, h5);
            hp.w = pk2u(h6, h7);
            Bh = __builtin_bit_cast(half8, hp);
            hqs[buf][tt][lane] = hp;           // ds_write only -- never waited on
        }
    };

    // ---- wave2: proj + pool for one published chunk ----
    const half8 sl8 = {(_Float16)RRELU_SLOPE, (_Float16)RRELU_SLOPE,
                       (_Float16)RRELU_SLOPE, (_Float16)RRELU_SLOPE,
                       (_Float16)RRELU_SLOPE, (_Float16)RRELU_SLOPE,
                       (_Float16)RRELU_SLOPE, (_Float16)RRELU_SLOPE};
    auto w2_process = [&](int c, int buf) {
        #pragma unroll
        for (int tt = 0; tt < TCH; ++tt) {
            const int t = c*TCH + tt;
            const uint4 hv = hqs[buf][tt][lane];
            const half8 h8 = __builtin_bit_cast(half8, hv);
            const half8 a8 = __builtin_elementwise_max(h8, h8 * sl8); // RReLU
            const f32x4 p  = hmfma32(ApF, a8, biasP);
            const f32x4 q4 = p * p;             // channels 4g+r of batch c16
            if ((tt & 1) == 0) {                // t even (chunk base even)
                const f32x4 pr = Wc + q4;       // closes window t/2 - 1
                if (t >= 2) {
                    const float mloc = fmaxf(fmaxf(pr[0], pr[1]),
                                             fmaxf(pr[2], pr[3]));
                    pbuf[c16*4 + g] = mloc;     // intra-wave, DS FIFO ordered
                    if (g == 0) {
                        const f32x4 pv = *(const f32x4*)&pbuf[c16*4];
                        const float mm = fmaxf(fmaxf(pv[0], pv[1]),
                                               fmaxf(pv[2], pv[3]));
                        outrow[(t >> 1) - 1] = __builtin_amdgcn_sqrtf(mm);
                    }
                }
                Wc = q4;                        // opens window t/2
            } else {
                Wc = Wc + q4;
            }
        }
    };

    // ---- prologue: wave1 fills chunk 0 (buf0) and prefetches chunk 1 ----
    if (wid == 1) {
        w1_load(0, xsA);
        w1_compute(0, xsA);
        w1_load(1, xsA);
    }
    __syncthreads();

    // ---- main loop, unrolled x2 (NCHUNK = 128, even) ----
    for (int cc = 0; cc < NCHUNK; cc += 2) {
        // sub A: chunk cc (buffers 0)
        if (wid == 0) {
            w0_chunk(0);
        } else if (wid == 1) {
            w1_load(cc + 2, xsB);      // issue loads first (latency cover)
            w1_compute(1, xsA);        // xz' for chunk cc+1 -> buf1
        } else {
            if (cc > 0) w2_process(cc - 1, 1);
        }
        __syncthreads();
        // sub B: chunk cc+1 (buffers 1)
        if (wid == 0) {
            w0_chunk(1);
        } else if (wid == 1) {
            w1_load(cc + 3, xsA);
            w1_compute(0, xsB);        // xz' for chunk cc+2 -> buf0
        } else {
            w2_process(cc, 0);
        }
        __syncthreads();
    }
    if (wid == 2) w2_process(NCHUNK - 1, 1);
}

extern "C" void kernel_launch(void* const* d_in, const int* in_sizes, int n_in,
                              void* d_out, int out_size, void* d_ws, size_t ws_size,
                              hipStream_t stream) {
    const float* x      = (const float*)d_in[0];
    const float* W_ih   = (const float*)d_in[1];
    const float* W_hh   = (const float*)d_in[2];
    const float* b_ih   = (const float*)d_in[3];
    const float* b_hh   = (const float*)d_in[4];
    const float* W_proj = (const float*)d_in[5];
    const float* b_proj = (const float*)d_in[6];
    float* out = (float*)d_out;

    dim3 grid(B_ROWS / 16);   // 256 chains; 3 waves (3 SIMDs) per chain
    dim3 block(192);
    hipLaunchKernelGGL(rnn_mfma_kernel, grid, block, 0, stream,
                       x, W_ih, W_hh, b_ih, b_hh, W_proj, b_proj, out);
}

// Round 18
// 314.550 us; speedup vs baseline: 2.1831x; 1.0508x over previous
//
#include <hip/hip_runtime.h>
#include <math.h>

#define T_LEN   2048
#define B_ROWS  4096
#define F_IN    16
#define HID     32
#define NCH     12
#define L_OUT   1023
#define TCH     16                 // timesteps per chunk (= sync granularity)
#define NCHUNK  (T_LEN / TCH)
#define RRELU_SLOPE 0.229f
#define ZSCALE  2.8853900817779268f   // 2*log2(e), folded into W_ih/W_hh/biases

typedef _Float16 half4 __attribute__((ext_vector_type(4)));
typedef _Float16 half8 __attribute__((ext_vector_type(8)));
typedef float    f32x4 __attribute__((ext_vector_type(4)));

// mfma_f32_16x16x16f16 (R7-R17 validated on gfx950):
// A: row = lane&15, k = 4*(lane>>4)+i ; B: col = lane&15, k = 4*(lane>>4)+i
// D: col = lane&15, row = 4*(lane>>4)+reg  -> D layout == next B layout
__device__ __forceinline__ f32x4 mfma16(half4 a, half4 b, f32x4 c) {
    return __builtin_amdgcn_mfma_f32_16x16x16f16(a, b, c, 0, 0, 0);
}

// K=32 fragment = concat of two K=16 fragments (R12-validated on gfx950).
__device__ __forceinline__ f32x4 hmfma32(half8 a, half8 b, f32x4 c) {
#if __has_builtin(__builtin_amdgcn_mfma_f32_16x16x32_f16)
    return __builtin_amdgcn_mfma_f32_16x16x32_f16(a, b, c, 0, 0, 0);
#else
    const uint4 ua = __builtin_bit_cast(uint4, a);
    const uint4 ub = __builtin_bit_cast(uint4, b);
    uint2 t;
    t.x = ua.x; t.y = ua.y; const half4 alo = __builtin_bit_cast(half4, t);
    t.x = ua.z; t.y = ua.w; const half4 ahi = __builtin_bit_cast(half4, t);
    t.x = ub.x; t.y = ub.y; const half4 blo = __builtin_bit_cast(half4, t);
    t.x = ub.z; t.y = ub.w; const half4 bhi = __builtin_bit_cast(half4, t);
    return mfma16(ahi, bhi, mfma16(alo, blo, c));
#endif
}

__device__ __forceinline__ unsigned pk2u(float a, float b) {
    return __builtin_bit_cast(unsigned, __builtin_amdgcn_cvt_pkrtz(a, b));
}
__device__ __forceinline__ half4 pack4(float a, float b, float c, float d) {
    uint2 u; u.x = pk2u(a, b); u.y = pk2u(c, d);
    return __builtin_bit_cast(half4, u);
}
__device__ __forceinline__ uint4 u4(f32x4 v) { return __builtin_bit_cast(uint4, v); }
__device__ __forceinline__ f32x4 f4(uint4 v) { return __builtin_bit_cast(f32x4, v); }

// Three waves per chain (three SIMDs) -- exact R12 structure (309 us best).
// Only the reciprocal block differs: PAIRWISE shared rcp (8 rcp -> 4 rcp,
// +12 muls, all pairs parallel -- no R17-style serial chain).
__global__ __launch_bounds__(192, 1)
void rnn_mfma_kernel(const float* __restrict__ x,
                     const float* __restrict__ W_ih,
                     const float* __restrict__ W_hh,
                     const float* __restrict__ b_ih,
                     const float* __restrict__ b_hh,
                     const float* __restrict__ W_proj,
                     const float* __restrict__ b_proj,
                     float* __restrict__ out)
{
    __shared__ alignas(16) uint4 hqs[2][TCH][64];    // packed h,   32 KB
    __shared__ alignas(16) uint4 xza_s[2][TCH][64];  // xz' lo blk, 32 KB (f32x4)
    __shared__ alignas(16) uint4 xzb_s[2][TCH][64];  // xz' hi blk, 32 KB
    __shared__ alignas(16) float pbuf[64];           // wave2 cross-g partials

    const int tid  = threadIdx.x;
    const int wid  = tid >> 6;         // 0=recurrence, 1=x-prep, 2=proj/pool
    const int lane = tid & 63;
    const int c16  = lane & 15;        // batch column
    const int g    = lane >> 4;        // k-block / D row-block
    const int rowBase = blockIdx.x * 16;

    const f32x4 zero4 = {0.0f, 0.0f, 0.0f, 0.0f};

    const float4* xsrc = (const float4*)x;
    const size_t xrow = (size_t)(rowBase + c16) * T_LEN;
    float* outrow = out + (size_t)(rowBase + c16) * L_OUT;

    // ---- per-wave weight fragments ----
    half8 AhhF[2];                     // K=32 fragments for the two unit-blocks
    half4 Aih[2];
    half8 ApF;
    f32x4 biasA = zero4, biasB = zero4, biasP = zero4;
    float4 xsA[TCH], xsB[TCH];         // wave1 load ping-pong

    if (wid == 0) {
        #pragma unroll
        for (int U = 0; U < 2; ++U) {
            half8 f;
            #pragma unroll
            for (int V = 0; V < 2; ++V)
                #pragma unroll
                for (int i = 0; i < 4; ++i)
                    f[V*4 + i] = (_Float16)(ZSCALE *
                        W_hh[(U*16 + c16)*HID + V*16 + 4*g + i]);
            AhhF[U] = f;
        }
    } else if (wid == 1) {
        #pragma unroll
        for (int U = 0; U < 2; ++U)
            #pragma unroll
            for (int i = 0; i < 4; ++i)
                Aih[U][i] = (_Float16)(ZSCALE *
                    W_ih[(U*16 + c16)*F_IN + 4*g + i]);
        #pragma unroll
        for (int r = 0; r < 4; ++r) {
            const int u = 4*g + r;
            biasA[r] = ZSCALE * (b_ih[u]      + b_hh[u]);
            biasB[r] = ZSCALE * (b_ih[16 + u] + b_hh[16 + u]);
        }
    } else {
        #pragma unroll
        for (int V = 0; V < 2; ++V)
            #pragma unroll
            for (int i = 0; i < 4; ++i)
                ApF[V*4 + i] = (c16 < NCH)
                    ? (_Float16)W_proj[c16*HID + V*16 + 4*g + i]
                    : (_Float16)0.0f;
        #pragma unroll
        for (int r = 0; r < 4; ++r) {
            const int u = 4*g + r;
            biasP[r] = (u < NCH) ? b_proj[u] : 0.0f;  // pad rows -> p=0 (max-safe)
        }
    }

    // wave0 recurrent state: h as the K=32 B fragment (lo16 | hi16)
    half8 Bh = {0,0,0,0,0,0,0,0};
    f32x4 Wc = zero4;                  // wave2 pool window accumulator

    // ---- wave1 helpers ----
    auto w1_load = [&](int c, float4* xs) {
        const int cc = (c < NCHUNK) ? c : NCHUNK - 1;
        #pragma unroll
        for (int m = 0; m < TCH; ++m)
            xs[m] = xsrc[(xrow + cc*TCH + m) * 4 + g];
    };
    auto w1_compute = [&](int buf, const float4* xs) {
        #pragma unroll
        for (int m = 0; m < TCH; ++m) {
            const half4 Bx = pack4(xs[m].x, xs[m].y, xs[m].z, xs[m].w);
            xza_s[buf][m][lane] = u4(mfma16(Aih[0], Bx, biasA));
            xzb_s[buf][m][lane] = u4(mfma16(Aih[1], Bx, biasB));
        }
    };

    // ---- wave0: one chunk of the sequential core (4-deep xz prefetch) ----
    auto w0_chunk = [&](int buf) {
        uint4 ra[4], rb[4];
        #pragma unroll
        for (int i = 0; i < 4; ++i) {
            ra[i] = xza_s[buf][i][lane];
            rb[i] = xzb_s[buf][i][lane];
        }
        #pragma unroll
        for (int tt = 0; tt < TCH; ++tt) {
            const f32x4 xza = f4(ra[tt & 3]);
            const f32x4 xzb = f4(rb[tt & 3]);
            // two independent K=32 MFMAs: z' = ZSCALE*(W*[x;h] + bias)
            const f32x4 za = hmfma32(AhhF[0], Bh, xza);
            const f32x4 zb = hmfma32(AhhF[1], Bh, xzb);
            if (tt + 4 < TCH) {                 // prefetch 4 steps ahead
                ra[tt & 3] = xza_s[buf][tt + 4][lane];
                rb[tt & 3] = xzb_s[buf][tt + 4][lane];
            }
            // tanh = 1 - 2/(exp2(z') + 1); PAIRWISE shared reciprocal:
            // r01 = rcp(d0*d1) -> i0 = d1*r01, i1 = d0*r01 (4 pairs, parallel)
            const float e0 = __builtin_amdgcn_exp2f(za[0]);
            const float e1 = __builtin_amdgcn_exp2f(za[1]);
            const float e2 = __builtin_amdgcn_exp2f(za[2]);
            const float e3 = __builtin_amdgcn_exp2f(za[3]);
            const float e4 = __builtin_amdgcn_exp2f(zb[0]);
            const float e5 = __builtin_amdgcn_exp2f(zb[1]);
            const float e6 = __builtin_amdgcn_exp2f(zb[2]);
            const float e7 = __builtin_amdgcn_exp2f(zb[3]);
            const float d0 = e0 + 1.0f, d1 = e1 + 1.0f;
            const float d2 = e2 + 1.0f, d3 = e3 + 1.0f;
            const float d4 = e4 + 1.0f, d5 = e5 + 1.0f;
            const float d6 = e6 + 1.0f, d7 = e7 + 1.0f;
            const float r01 = __builtin_amdgcn_rcpf(d0 * d1);
            const float r23 = __builtin_amdgcn_rcpf(d2 * d3);
            const float r45 = __builtin_amdgcn_rcpf(d4 * d5);
            const float r67 = __builtin_amdgcn_rcpf(d6 * d7);
            const float i0 = d1 * r01, i1 = d0 * r01;
            const float i2 = d3 * r23, i3 = d2 * r23;
            const float i4 = d5 * r45, i5 = d4 * r45;
            const float i6 = d7 * r67, i7 = d6 * r67;
            const float h0 = fmaf(-2.0f, i0, 1.0f);
            const float h1 = fmaf(-2.0f, i1, 1.0f);
            const float h2 = fmaf(-2.0f, i2, 1.0f);
            const float h3 = fmaf(-2.0f, i3, 1.0f);
            const float h4 = fmaf(-2.0f, i4, 1.0f);
            const float h5 = fmaf(-2.0f, i5, 1.0f);
            const float h6 = fmaf(-2.0f, i6, 1.0f);
            const float h7 = fmaf(-2.0f, i7, 1.0f);
            uint4 hp;
            hp.x = pk2u(h0, h1);
            hp.y = pk2u(h2, h3);
            hp.z = pk2u(h4, h5);
            hp.w = pk2u(h6, h7);
            Bh = __builtin_bit_cast(half8, hp);
            hqs[buf][tt][lane] = hp;           // ds_write only -- never waited on
        }
    };

    // ---- wave2: proj + pool for one published chunk ----
    const half8 sl8 = {(_Float16)RRELU_SLOPE, (_Float16)RRELU_SLOPE,
                       (_Float16)RRELU_SLOPE, (_Float16)RRELU_SLOPE,
                       (_Float16)RRELU_SLOPE, (_Float16)RRELU_SLOPE,
                       (_Float16)RRELU_SLOPE, (_Float16)RRELU_SLOPE};
    auto w2_process = [&](int c, int buf) {
        #pragma unroll
        for (int tt = 0; tt < TCH; ++tt) {
            const int t = c*TCH + tt;
            const uint4 hv = hqs[buf][tt][lane];
            const half8 h8 = __builtin_bit_cast(half8, hv);
            const half8 a8 = __builtin_elementwise_max(h8, h8 * sl8); // RReLU
            const f32x4 p  = hmfma32(ApF, a8, biasP);
            const f32x4 q4 = p * p;             // channels 4g+r of batch c16
            if ((tt & 1) == 0) {                // t even (chunk base even)
                const f32x4 pr = Wc + q4;       // closes window t/2 - 1
                if (t >= 2) {
                    const float mloc = fmaxf(fmaxf(pr[0], pr[1]),
                                             fmaxf(pr[2], pr[3]));
                    pbuf[c16*4 + g] = mloc;     // intra-wave, DS FIFO ordered
                    if (g == 0) {
                        const f32x4 pv = *(const f32x4*)&pbuf[c16*4];
                        const float mm = fmaxf(fmaxf(pv[0], pv[1]),
                                               fmaxf(pv[2], pv[3]));
                        outrow[(t >> 1) - 1] = __builtin_amdgcn_sqrtf(mm);
                    }
                }
                Wc = q4;                        // opens window t/2
            } else {
                Wc = Wc + q4;
            }
        }
    };

    // ---- prologue: wave1 fills chunk 0 (buf0) and prefetches chunk 1 ----
    if (wid == 1) {
        w1_load(0, xsA);
        w1_compute(0, xsA);
        w1_load(1, xsA);
    }
    __syncthreads();

    // ---- main loop, unrolled x2 (NCHUNK = 128, even) ----
    for (int cc = 0; cc < NCHUNK; cc += 2) {
        // sub A: chunk cc (buffers 0)
        if (wid == 0) {
            w0_chunk(0);
        } else if (wid == 1) {
            w1_load(cc + 2, xsB);      // issue loads first (latency cover)
            w1_compute(1, xsA);        // xz' for chunk cc+1 -> buf1
        } else {
            if (cc > 0) w2_process(cc - 1, 1);
        }
        __syncthreads();
        // sub B: chunk cc+1 (buffers 1)
        if (wid == 0) {
            w0_chunk(1);
        } else if (wid == 1) {
            w1_load(cc + 3, xsA);
            w1_compute(0, xsB);        // xz' for chunk cc+2 -> buf0
        } else {
            w2_process(cc, 0);
        }
        __syncthreads();
    }
    if (wid == 2) w2_process(NCHUNK - 1, 1);
}

extern "C" void kernel_launch(void* const* d_in, const int* in_sizes, int n_in,
                              void* d_out, int out_size, void* d_ws, size_t ws_size,
                              hipStream_t stream) {
    const float* x      = (const float*)d_in[0];
    const float* W_ih   = (const float*)d_in[1];
    const float* W_hh   = (const float*)d_in[2];
    const float* b_ih   = (const float*)d_in[3];
    const float* b_hh   = (const float*)d_in[4];
    const float* W_proj = (const float*)d_in[5];
    const float* b_proj = (const float*)d_in[6];
    float* out = (float*)d_out;

    dim3 grid(B_ROWS / 16);   // 256 chains; 3 waves (3 SIMDs) per chain
    dim3 block(192);
    hipLaunchKernelGGL(rnn_mfma_kernel, grid, block, 0, stream,
                       x, W_ih, W_hh, b_ih, b_hh, W_proj, b_proj, out);
}